// Round 3
// baseline (563.356 us; speedup 1.0000x reference)
//
#include <hip/hip_runtime.h>
#include <hip/hip_bf16.h>
#include <math.h>

typedef __hip_bfloat16 bf;

#define BB   16     // batch
#define CC   128    // channels
#define LL   4096   // H*W
#define DM   32     // d_model per chunk
#define DI   64     // d_inner
#define DSN  16     // d_state
#define GG   64     // 4 * BB sequences
#define NC   32     // scan chunks
#define CL   128    // LL / NC
#define TL   64     // l-tile for k1/k6
#define NCOLK1 (TL + 3)

__device__ __forceinline__ float bf2f(bf x) { return __bfloat162float(x); }
__device__ __forceinline__ bf f2bf(float x) { return __float2bfloat16(x); }
__device__ __forceinline__ float blo(unsigned v) { return __uint_as_float(v << 16); }
__device__ __forceinline__ float bhi(unsigned v) { return __uint_as_float(v & 0xffff0000u); }
__device__ __forceinline__ unsigned pack2(float a, float b) {
  bf ba = f2bf(a), bb = f2bf(b);
  unsigned short ua = *(unsigned short*)&ba, ub = *(unsigned short*)&bb;
  return (unsigned)ua | ((unsigned)ub << 16);
}

#if __has_builtin(__builtin_amdgcn_exp2f)
#define EXP2F(x) __builtin_amdgcn_exp2f(x)
#else
#define EXP2F(x) exp2f(x)
#endif

__device__ __forceinline__ float sigmoidf_(float x) { return 1.0f / (1.0f + __expf(-x)); }
__device__ __forceinline__ float softplusf_(float x) {
  return fmaxf(x, 0.0f) + log1pf(__expf(-fabsf(x)));
}
__device__ __forceinline__ void unpack8(uint4 v, float* o) {
  o[0] = blo(v.x); o[1] = bhi(v.x); o[2] = blo(v.y); o[3] = bhi(v.y);
  o[4] = blo(v.z); o[5] = bhi(v.z); o[6] = blo(v.w); o[7] = bhi(v.w);
}

// ---------------- K1: layernorm + in_proj(xi half) + causal conv + silu -> u (bf16), xn (bf16) ----------------
// grid: BB * (LL/TL) = 1024 blocks, 256 threads. thread = (g, d).
__global__ __launch_bounds__(256) void k1_ln_conv(
    const float* __restrict__ input, const float* __restrict__ ln_g, const float* __restrict__ ln_b,
    const float* __restrict__ in_proj_w, const float* __restrict__ conv_w, const float* __restrict__ conv_b,
    bf* __restrict__ u_ws, bf* __restrict__ xn_ws) {
  __shared__ float xnT[NCOLK1][132];   // [col j][channel c]
  __shared__ float mu_s[NCOLK1], rs_s[NCOLK1];
  int b = blockIdx.x >> 6;
  int tile = blockIdx.x & 63;
  int l0 = tile * TL;
  int tid = threadIdx.x;
  const float* inb = input + (size_t)b * CC * LL;
  for (int i = tid; i < CC * NCOLK1; i += 256) {
    int c = i / NCOLK1, j = i - c * NCOLK1;
    int l = l0 - 3 + j;
    xnT[j][c] = (l >= 0) ? inb[c * LL + l] : 0.0f;
  }
  __syncthreads();
  if (tid < NCOLK1) {
    float s = 0.f, s2 = 0.f;
    for (int c = 0; c < CC; c++) { float v = xnT[tid][c]; s += v; s2 = fmaf(v, v, s2); }
    float mu = s * (1.0f / CC);
    float var = s2 * (1.0f / CC) - mu * mu;
    mu_s[tid] = mu;
    rs_s[tid] = rsqrtf(var + 1e-5f);
  }
  __syncthreads();
  for (int i = tid; i < CC * NCOLK1; i += 256) {
    int c = i / NCOLK1, j = i - c * NCOLK1;
    xnT[j][c] = (xnT[j][c] - mu_s[j]) * rs_s[j] * ln_g[c] + ln_b[c];
  }
  __syncthreads();
  // flush xn (bf16) for k6: [b][c][l] layout, coalesced over l
  for (int i = tid; i < CC * TL; i += 256) {
    int c = i >> 6, j = i & 63;
    xn_ws[((size_t)(b * CC + c)) * LL + l0 + j] = f2bf(xnT[j + 3][c]);
  }
  int g = tid >> 6, d = tid & 63;
  float w[32];
#pragma unroll
  for (int r = 0; r < 32; r++) w[r] = in_proj_w[d * DM + r];
  float cw0 = conv_w[d * 4 + 0], cw1 = conv_w[d * 4 + 1];
  float cw2 = conv_w[d * 4 + 2], cw3 = conv_w[d * 4 + 3];
  float cb = conv_b[d];
  int s_idx = g * BB + b;
  bf* uo = u_ws + (size_t)s_idx * LL * DI;
  float x3 = 0.f, x2 = 0.f, x1 = 0.f, x0 = 0.f;
  for (int j = 0; j < NCOLK1; j++) {
    int l = l0 - 3 + j;
    float xi = 0.f;
    if (l >= 0) {
      const float4* xp4 = (const float4*)&xnT[j][g * DM];  // wave-uniform addr -> broadcast
      float acc = 0.f;
#pragma unroll
      for (int q = 0; q < 8; q++) {
        float4 v = xp4[q];
        acc += v.x * w[q * 4 + 0] + v.y * w[q * 4 + 1] + v.z * w[q * 4 + 2] + v.w * w[q * 4 + 3];
      }
      xi = acc;
    }
    x3 = x2; x2 = x1; x1 = x0; x0 = xi;
    if (l >= l0) {
      float pre = x3 * cw0 + x2 * cw1 + x1 * cw2 + x0 * cw3 + cb;
      float uu = pre * sigmoidf_(pre);
      uo[(size_t)l * DI + d] = f2bf(uu);
    }
  }
}

// ---------------- K2: x_proj + dt_proj + softplus -> delta, B, C (bf16), LDS-staged coalesced ----------------
// grid: GG*LL/256 = 1024 blocks, 256 threads; one position per thread, all IO via LDS.
__global__ __launch_bounds__(256) void k2_xproj(
    const bf* __restrict__ u_ws, const float* __restrict__ x_proj_w,
    const float* __restrict__ dt_proj_w, const float* __restrict__ dt_proj_b,
    bf* __restrict__ delta_ws, bf* __restrict__ Bws, bf* __restrict__ Cws) {
  __shared__ unsigned uS[256 * 33];      // 256 rows x 32 dwords, stride 33 (odd) -> conflict-free
  __shared__ unsigned bcS[2][256 * 9];   // B/C staging, stride 9
  int tid = threadIdx.x;
  size_t pos0 = (size_t)blockIdx.x * 256;
  const unsigned* src = (const unsigned*)u_ws + pos0 * 32;
#pragma unroll
  for (int k = 0; k < 32; k++) {         // coalesced fill: 8192 dwords
    int idx = tid + k * 256;
    uS[(idx >> 5) * 33 + (idx & 31)] = src[idx];
  }
  __syncthreads();
  float u[DI];
#pragma unroll
  for (int k = 0; k < 32; k++) {         // own row: banks (tid+k)%32, conflict-free
    unsigned v = uS[tid * 33 + k];
    u[2 * k] = blo(v); u[2 * k + 1] = bhi(v);
  }
  float xdb[34];
  for (int e = 0; e < 34; e++) {         // wave-uniform weights -> s_load
    const float* w = x_proj_w + e * DI;
    float acc = 0.f;
#pragma unroll
    for (int dp = 0; dp < DI; dp++) acc = fmaf(u[dp], w[dp], acc);
    xdb[e] = acc;
  }
#pragma unroll
  for (int n = 0; n < 8; n++) bcS[0][tid * 9 + n] = pack2(xdb[2 + 2 * n], xdb[3 + 2 * n]);
#pragma unroll
  for (int n = 0; n < 8; n++) bcS[1][tid * 9 + n] = pack2(xdb[18 + 2 * n], xdb[19 + 2 * n]);
  float dt0 = xdb[0], dt1 = xdb[1];
  // delta into own uS row (only this thread reads/writes row tid -> no barrier needed)
  for (int d2 = 0; d2 < 32; d2++) {
    float r0 = softplusf_(dt0 * dt_proj_w[4 * d2 + 0] + dt1 * dt_proj_w[4 * d2 + 1] + dt_proj_b[2 * d2]);
    float r1 = softplusf_(dt0 * dt_proj_w[4 * d2 + 2] + dt1 * dt_proj_w[4 * d2 + 3] + dt_proj_b[2 * d2 + 1]);
    uS[tid * 33 + d2] = pack2(r0, r1);
  }
  __syncthreads();
  unsigned* ddst = (unsigned*)delta_ws + pos0 * 32;
#pragma unroll
  for (int k = 0; k < 32; k++) {         // coalesced flush
    int idx = tid + k * 256;
    ddst[idx] = uS[(idx >> 5) * 33 + (idx & 31)];
  }
  unsigned* bdst = (unsigned*)Bws + pos0 * 8;
  unsigned* cdst = (unsigned*)Cws + pos0 * 8;
#pragma unroll
  for (int k = 0; k < 8; k++) {
    int idx = tid + k * 256;
    bdst[idx] = bcS[0][(idx >> 3) * 9 + (idx & 7)];
  }
#pragma unroll
  for (int k = 0; k < 8; k++) {
    int idx = tid + k * 256;
    cdst[idx] = bcS[1][(idx >> 3) * 9 + (idx & 7)];
  }
}

// ---------------- K3: scan pass A — local states + chunk transition products ----------------
// grid: GG*NC = 2048 blocks, 64 threads (1 wave, lane = d).
__global__ __launch_bounds__(64) void k3_scanA(
    const bf* __restrict__ delta_ws, const bf* __restrict__ u_ws, const bf* __restrict__ Bws,
    const float* __restrict__ A_log, float* __restrict__ hloc, float* __restrict__ Aprod) {
  int s = blockIdx.x / NC, chunk = blockIdx.x % NC;
  int d = threadIdx.x;
  float A2[DSN];
#pragma unroll
  for (int n = 0; n < DSN; n++)
    A2[n] = -__expf(A_log[d * DSN + n]) * 1.44269504088896f;  // A * log2(e)
  float h[DSN];
#pragma unroll
  for (int n = 0; n < DSN; n++) h[n] = 0.f;
  float ssum = 0.f;
  size_t base = (size_t)s * LL + (size_t)chunk * CL;
  const unsigned short* dp = (const unsigned short*)delta_ws + base * DI + d;
  const unsigned short* up = (const unsigned short*)u_ws + base * DI + d;
  const uint4* bp = (const uint4*)(Bws + base * DSN);
  for (int t = 0; t < CL; t++) {
    float delta = __uint_as_float((unsigned)dp[(size_t)t * DI] << 16);
    float uu    = __uint_as_float((unsigned)up[(size_t)t * DI] << 16);
    float Bv[16];
    unpack8(bp[t * 2], Bv); unpack8(bp[t * 2 + 1], Bv + 8);
    float du = delta * uu;
    ssum += delta;
#pragma unroll
    for (int n = 0; n < DSN; n++) {
      float e = EXP2F(delta * A2[n]);
      h[n] = fmaf(h[n], e, du * Bv[n]);
    }
  }
  size_t ob = (size_t)blockIdx.x * (DSN * DI) + d;
#pragma unroll
  for (int n = 0; n < DSN; n++) {
    hloc[ob + n * DI] = h[n];
    Aprod[ob + n * DI] = EXP2F(A2[n] * ssum);
  }
}

// ---------------- K4: sequential cross-chunk combine -> per-chunk initial states ----------------
// grid: GG blocks, 64 threads.
__global__ __launch_bounds__(64) void k4_combine(
    const float* __restrict__ hloc, const float* __restrict__ Aprod, float* __restrict__ hin) {
  int s = blockIdx.x, d = threadIdx.x;
  float h[DSN];
#pragma unroll
  for (int n = 0; n < DSN; n++) h[n] = 0.f;
  for (int k = 0; k < NC; k++) {
    size_t base = (size_t)(s * NC + k) * (DSN * DI) + d;
#pragma unroll
    for (int n = 0; n < DSN; n++) {
      hin[base + n * DI] = h[n];
      h[n] = fmaf(h[n], Aprod[base + n * DI], hloc[base + n * DI]);
    }
  }
}

// ---------------- K5: scan pass C — replay with h_in, emit y2 = y + u*D (bf16, in-place over delta) ----------------
// grid: GG*NC = 2048 blocks, 64 threads. dy holds delta on entry; y2 overwrites it element-by-element
// (each element read before written, per-lane program order; same thread owns both).
__global__ __launch_bounds__(64) void k5_scanC(
    bf* dy, const bf* __restrict__ u_ws,
    const bf* __restrict__ Bws, const bf* __restrict__ Cws,
    const float* __restrict__ A_log, const float* __restrict__ Dw,
    const float* __restrict__ hin) {
  int s = blockIdx.x / NC, chunk = blockIdx.x % NC;
  int d = threadIdx.x;
  float A2[DSN];
#pragma unroll
  for (int n = 0; n < DSN; n++)
    A2[n] = -__expf(A_log[d * DSN + n]) * 1.44269504088896f;
  float Dd = Dw[d];
  float h[DSN];
  size_t hb = (size_t)blockIdx.x * (DSN * DI) + d;
#pragma unroll
  for (int n = 0; n < DSN; n++) h[n] = hin[hb + n * DI];
  size_t base = (size_t)s * LL + (size_t)chunk * CL;
  unsigned short* dyp = (unsigned short*)dy + base * DI + d;
  const unsigned short* up = (const unsigned short*)u_ws + base * DI + d;
  const uint4* bp = (const uint4*)(Bws + base * DSN);
  const uint4* cp = (const uint4*)(Cws + base * DSN);
  for (int t = 0; t < CL; t++) {
    float delta = __uint_as_float((unsigned)dyp[(size_t)t * DI] << 16);
    float uu    = __uint_as_float((unsigned)up[(size_t)t * DI] << 16);
    float Bv[16], Cv[16];
    unpack8(bp[t * 2], Bv); unpack8(bp[t * 2 + 1], Bv + 8);
    unpack8(cp[t * 2], Cv); unpack8(cp[t * 2 + 1], Cv + 8);
    float du = delta * uu;
    float y = 0.f;
#pragma unroll
    for (int n = 0; n < DSN; n++) {
      float e = EXP2F(delta * A2[n]);
      h[n] = fmaf(h[n], e, du * Bv[n]);
      y = fmaf(h[n], Cv[n], y);
    }
    bf r = f2bf(y + uu * Dd);
    dyp[(size_t)t * DI] = *(unsigned short*)&r;
  }
}

// ---------------- K6: z-gate + out_proj + residual -> output (fp32). Reads xn(bf16), y2(bf16). ----------------
// grid: BB * (LL/TL) = 1024 blocks, 256 threads; thread = (g, column j).
__global__ __launch_bounds__(256) void k6_final(
    const bf* __restrict__ xn_ws, const float* __restrict__ in_proj_w,
    const float* __restrict__ out_proj_w, const bf* __restrict__ y2ws,
    float* __restrict__ out) {
  __shared__ unsigned short xnS[CC][66];   // row stride 33 dwords (odd) -> conflict-free
  __shared__ unsigned y2S[4][64 * 33];     // per-g: 64 rows x 32 dwords, stride 33
  int b = blockIdx.x >> 6;
  int tile = blockIdx.x & 63;
  int l0 = tile * TL;
  int tid = threadIdx.x;
  const unsigned* xsrc = (const unsigned*)xn_ws;
#pragma unroll
  for (int k = 0; k < 16; k++) {           // xn tile: 4096 dwords, coalesced
    int idx = tid + k * 256;
    int c = idx >> 5, dw = idx & 31;
    ((unsigned*)&xnS[c][0])[dw] = xsrc[(((size_t)(b * CC + c)) * LL + l0) / 2 + dw];
  }
#pragma unroll
  for (int k = 0; k < 32; k++) {           // y2 tile: 8192 dwords, coalesced per g-chunk
    int idx = tid + k * 256;
    int g = idx >> 11, rem = idx & 2047;
    const unsigned* ysrc = (const unsigned*)(y2ws + (((size_t)(g * BB + b)) * LL + l0) * DI);
    y2S[g][(rem >> 5) * 33 + (rem & 31)] = ysrc[rem];
  }
  __syncthreads();
  int j = tid & 63, g = tid >> 6;
  float xcol[32];
#pragma unroll
  for (int r = 0; r < 32; r++)
    xcol[r] = __uint_as_float((unsigned)xnS[g * 32 + r][j] << 16);
  float acc[DI];
  for (int d = 0; d < DI; d++) {           // z projection; weights wave-uniform -> s_load
    const float* w = in_proj_w + (DI + d) * DM;
    float a = 0.f;
#pragma unroll
    for (int r = 0; r < 32; r++) a = fmaf(xcol[r], w[r], a);
    acc[d] = a;
  }
  const unsigned* yrow = &y2S[g][j * 33];  // banks (j+k)%32, conflict-free
#pragma unroll
  for (int k = 0; k < 32; k++) {           // gate: y3 = y2 * silu(z)
    unsigned v = yrow[k];
    float z0 = acc[2 * k], z1 = acc[2 * k + 1];
    acc[2 * k]     = blo(v) * (z0 * sigmoidf_(z0));
    acc[2 * k + 1] = bhi(v) * (z1 * sigmoidf_(z1));
  }
  float* ob = out + ((size_t)(b * CC + g * DM)) * LL + l0 + j;
  for (int jj = 0; jj < DM; jj++) {        // out_proj + residual; weights uniform -> s_load
    const float* w = out_proj_w + jj * DI;
    float a = __uint_as_float((unsigned)xnS[g * 32 + jj][j] << 16);  // residual xn
#pragma unroll
    for (int d = 0; d < DI; d++) a = fmaf(acc[d], w[d], a);
    ob[(size_t)jj * LL] = a;               // lanes j-consecutive: coalesced 256B
  }
}

extern "C" void kernel_launch(void* const* d_in, const int* in_sizes, int n_in,
                              void* d_out, int out_size, void* d_ws, size_t ws_size,
                              hipStream_t stream) {
  const float* input     = (const float*)d_in[0];
  const float* ln_g      = (const float*)d_in[1];
  const float* ln_b      = (const float*)d_in[2];
  const float* in_proj_w = (const float*)d_in[3];
  const float* conv_w    = (const float*)d_in[4];
  const float* conv_b    = (const float*)d_in[5];
  const float* x_proj_w  = (const float*)d_in[6];
  const float* dt_proj_w = (const float*)d_in[7];
  const float* dt_proj_b = (const float*)d_in[8];
  const float* A_log     = (const float*)d_in[9];
  const float* Dw        = (const float*)d_in[10];
  const float* out_proj_w= (const float*)d_in[11];
  float* out = (float*)d_out;

  char* ws = (char*)d_ws;
  bf*    u_ws     = (bf*)(ws);                    // 32 MiB
  bf*    delta_ws = (bf*)(ws + 33554432);         // 32 MiB (y2 aliases after k5)
  bf*    Bws      = (bf*)(ws + 67108864);         // 8 MiB
  bf*    Cws      = (bf*)(ws + 75497472);         // 8 MiB
  bf*    xn_ws    = (bf*)(ws + 83886080);         // 16 MiB
  float* hloc     = (float*)(ws + 100663296);     // 8 MiB
  float* Aprod    = (float*)(ws + 109051904);     // 8 MiB
  float* hin      = (float*)(ws + 117440512);     // 8 MiB
  (void)in_sizes; (void)n_in; (void)out_size; (void)ws_size;

  hipLaunchKernelGGL(k1_ln_conv, dim3(1024), dim3(256), 0, stream,
                     input, ln_g, ln_b, in_proj_w, conv_w, conv_b, u_ws, xn_ws);
  hipLaunchKernelGGL(k2_xproj, dim3(1024), dim3(256), 0, stream,
                     u_ws, x_proj_w, dt_proj_w, dt_proj_b, delta_ws, Bws, Cws);
  hipLaunchKernelGGL(k3_scanA, dim3(GG * NC), dim3(64), 0, stream,
                     delta_ws, u_ws, Bws, A_log, hloc, Aprod);
  hipLaunchKernelGGL(k4_combine, dim3(GG), dim3(64), 0, stream,
                     hloc, Aprod, hin);
  hipLaunchKernelGGL(k5_scanC, dim3(GG * NC), dim3(64), 0, stream,
                     delta_ws, u_ws, Bws, Cws, A_log, Dw, hin);
  hipLaunchKernelGGL(k6_final, dim3(1024), dim3(256), 0, stream,
                     xn_ws, in_proj_w, out_proj_w, delta_ws, out);
}

// Round 4
// 527.242 us; speedup vs baseline: 1.0685x; 1.0685x over previous
//
#include <hip/hip_runtime.h>
#include <hip/hip_bf16.h>
#include <math.h>

typedef __hip_bfloat16 bf;

#define BB   16     // batch
#define CC   128    // channels
#define LL   4096   // H*W
#define DM   32     // d_model per chunk
#define DI   64     // d_inner
#define DSN  16     // d_state
#define GG   64     // 4 * BB sequences
#define NC   32     // scan chunks
#define CL   128    // LL / NC
#define TL   64     // l-tile for k1/k6
#define NCOLK1 (TL + 3)

__device__ __forceinline__ float bf2f(bf x) { return __bfloat162float(x); }
__device__ __forceinline__ bf f2bf(float x) { return __float2bfloat16(x); }
__device__ __forceinline__ float blo(unsigned v) { return __uint_as_float(v << 16); }
__device__ __forceinline__ float bhi(unsigned v) { return __uint_as_float(v & 0xffff0000u); }
__device__ __forceinline__ unsigned pack2(float a, float b) {
  bf ba = f2bf(a), bb = f2bf(b);
  unsigned short ua = *(unsigned short*)&ba, ub = *(unsigned short*)&bb;
  return (unsigned)ua | ((unsigned)ub << 16);
}

#if __has_builtin(__builtin_amdgcn_exp2f)
#define EXP2F(x) __builtin_amdgcn_exp2f(x)
#else
#define EXP2F(x) exp2f(x)
#endif

__device__ __forceinline__ float sigmoidf_(float x) { return 1.0f / (1.0f + __expf(-x)); }
__device__ __forceinline__ float softplusf_(float x) {
  return fmaxf(x, 0.0f) + log1pf(__expf(-fabsf(x)));
}
__device__ __forceinline__ void unpack8(uint4 v, float* o) {
  o[0] = blo(v.x); o[1] = bhi(v.x); o[2] = blo(v.y); o[3] = bhi(v.y);
  o[4] = blo(v.z); o[5] = bhi(v.z); o[6] = blo(v.w); o[7] = bhi(v.w);
}

// ---------------- K1: layernorm + in_proj(xi half) + causal conv + silu -> u (bf16), xn (bf16) ----------------
// grid: BB * (LL/TL) = 1024 blocks, 256 threads. thread = (g, d).
__global__ __launch_bounds__(256) void k1_ln_conv(
    const float* __restrict__ input, const float* __restrict__ ln_g, const float* __restrict__ ln_b,
    const float* __restrict__ in_proj_w, const float* __restrict__ conv_w, const float* __restrict__ conv_b,
    bf* __restrict__ u_ws, bf* __restrict__ xn_ws) {
  __shared__ float xnT[NCOLK1][132];   // [col j][channel c]
  __shared__ float mu_s[NCOLK1], rs_s[NCOLK1];
  int b = blockIdx.x >> 6;
  int tile = blockIdx.x & 63;
  int l0 = tile * TL;
  int tid = threadIdx.x;
  const float* inb = input + (size_t)b * CC * LL;
  for (int i = tid; i < CC * NCOLK1; i += 256) {
    int c = i / NCOLK1, j = i - c * NCOLK1;
    int l = l0 - 3 + j;
    xnT[j][c] = (l >= 0) ? inb[c * LL + l] : 0.0f;
  }
  __syncthreads();
  if (tid < NCOLK1) {
    float s = 0.f, s2 = 0.f;
    for (int c = 0; c < CC; c++) { float v = xnT[tid][c]; s += v; s2 = fmaf(v, v, s2); }
    float mu = s * (1.0f / CC);
    float var = s2 * (1.0f / CC) - mu * mu;
    mu_s[tid] = mu;
    rs_s[tid] = rsqrtf(var + 1e-5f);
  }
  __syncthreads();
  for (int i = tid; i < CC * NCOLK1; i += 256) {
    int c = i / NCOLK1, j = i - c * NCOLK1;
    xnT[j][c] = (xnT[j][c] - mu_s[j]) * rs_s[j] * ln_g[c] + ln_b[c];
  }
  __syncthreads();
  // flush xn (bf16) for k6: [b][c][l] layout, coalesced over l
  for (int i = tid; i < CC * TL; i += 256) {
    int c = i >> 6, j = i & 63;
    xn_ws[((size_t)(b * CC + c)) * LL + l0 + j] = f2bf(xnT[j + 3][c]);
  }
  int g = tid >> 6, d = tid & 63;
  float w[32];
#pragma unroll
  for (int r = 0; r < 32; r++) w[r] = in_proj_w[d * DM + r];
  float cw0 = conv_w[d * 4 + 0], cw1 = conv_w[d * 4 + 1];
  float cw2 = conv_w[d * 4 + 2], cw3 = conv_w[d * 4 + 3];
  float cb = conv_b[d];
  int s_idx = g * BB + b;
  bf* uo = u_ws + (size_t)s_idx * LL * DI;
  float x3 = 0.f, x2 = 0.f, x1 = 0.f, x0 = 0.f;
  for (int j = 0; j < NCOLK1; j++) {
    int l = l0 - 3 + j;
    float xi = 0.f;
    if (l >= 0) {
      const float4* xp4 = (const float4*)&xnT[j][g * DM];  // wave-uniform addr -> broadcast
      float acc = 0.f;
#pragma unroll
      for (int q = 0; q < 8; q++) {
        float4 v = xp4[q];
        acc += v.x * w[q * 4 + 0] + v.y * w[q * 4 + 1] + v.z * w[q * 4 + 2] + v.w * w[q * 4 + 3];
      }
      xi = acc;
    }
    x3 = x2; x2 = x1; x1 = x0; x0 = xi;
    if (l >= l0) {
      float pre = x3 * cw0 + x2 * cw1 + x1 * cw2 + x0 * cw3 + cb;
      float uu = pre * sigmoidf_(pre);
      uo[(size_t)l * DI + d] = f2bf(uu);
    }
  }
}

// ---------------- K2: x_proj + dt_proj + softplus -> delta, B, C (bf16) ----------------
// grid: 1024 blocks, 256 threads; one position per thread; register-blocked (no spills);
// all global IO via LDS, coalesced.
__global__ __launch_bounds__(256) void k2_xproj(
    const bf* __restrict__ u_ws, const float* __restrict__ x_proj_w,
    const float* __restrict__ dt_proj_w, const float* __restrict__ dt_proj_b,
    bf* __restrict__ delta_ws, bf* __restrict__ Bws, bf* __restrict__ Cws) {
  __shared__ unsigned uS[256 * 33];      // 256 rows x 32 dwords, stride 33 (odd) -> conflict-free
  __shared__ unsigned bcS[2][256 * 9];   // B/C staging, stride 9
  int tid = threadIdx.x;
  size_t pos0 = (size_t)blockIdx.x * 256;
  const unsigned* src = (const unsigned*)u_ws + pos0 * 32;
#pragma unroll
  for (int k = 0; k < 32; k++) {         // coalesced fill
    int idx = tid + k * 256;
    uS[(idx >> 5) * 33 + (idx & 31)] = src[idx];
  }
  __syncthreads();
  float xdb[34];
#pragma unroll
  for (int e = 0; e < 34; e++) xdb[e] = 0.f;
  // register-blocked matvec: 4 chunks of 16 u-values; live regs ~ 16 + 34
#pragma unroll
  for (int c2 = 0; c2 < 4; c2++) {
    float f[16];
#pragma unroll
    for (int k = 0; k < 8; k++) {        // own row, banks (tid+k)%32 -> <=2-way (free)
      unsigned v = uS[tid * 33 + c2 * 8 + k];
      f[2 * k] = blo(v); f[2 * k + 1] = bhi(v);
    }
#pragma unroll
    for (int e = 0; e < 34; e++) {       // weights wave-uniform -> s_load
      const float* w = x_proj_w + e * DI + c2 * 16;
      float a = xdb[e];
#pragma unroll
      for (int i = 0; i < 16; i++) a = fmaf(f[i], w[i], a);
      xdb[e] = a;
    }
  }
#pragma unroll
  for (int n = 0; n < 8; n++) bcS[0][tid * 9 + n] = pack2(xdb[2 + 2 * n], xdb[3 + 2 * n]);
#pragma unroll
  for (int n = 0; n < 8; n++) bcS[1][tid * 9 + n] = pack2(xdb[18 + 2 * n], xdb[19 + 2 * n]);
  float dt0 = xdb[0], dt1 = xdb[1];
  // delta into own uS row (row owned by this thread -> no barrier needed before rewrite)
  for (int d2 = 0; d2 < 32; d2++) {
    float r0 = softplusf_(dt0 * dt_proj_w[4 * d2 + 0] + dt1 * dt_proj_w[4 * d2 + 1] + dt_proj_b[2 * d2]);
    float r1 = softplusf_(dt0 * dt_proj_w[4 * d2 + 2] + dt1 * dt_proj_w[4 * d2 + 3] + dt_proj_b[2 * d2 + 1]);
    uS[tid * 33 + d2] = pack2(r0, r1);
  }
  __syncthreads();
  unsigned* ddst = (unsigned*)delta_ws + pos0 * 32;
#pragma unroll
  for (int k = 0; k < 32; k++) {         // coalesced flush
    int idx = tid + k * 256;
    ddst[idx] = uS[(idx >> 5) * 33 + (idx & 31)];
  }
  unsigned* bdst = (unsigned*)Bws + pos0 * 8;
  unsigned* cdst = (unsigned*)Cws + pos0 * 8;
#pragma unroll
  for (int k = 0; k < 8; k++) {
    int idx = tid + k * 256;
    bdst[idx] = bcS[0][(idx >> 3) * 9 + (idx & 7)];
  }
#pragma unroll
  for (int k = 0; k < 8; k++) {
    int idx = tid + k * 256;
    cdst[idx] = bcS[1][(idx >> 3) * 9 + (idx & 7)];
  }
}

// Detect A2[n] == (n+1)*A2[0] (true for this problem's A = arange(1..16)); enables
// one-exp-per-step power chain in the scans. Guarded: falls back to general path.
__device__ __forceinline__ bool ladder_ok(const float* A2) {
  bool ok = true;
#pragma unroll
  for (int n = 0; n < DSN; n++) {
    float r = A2[n] / A2[0];
    ok = ok && (fabsf(r - (float)(n + 1)) < 1e-3f);
  }
  return ok;
}

// ---------------- K3: scan pass A — local states + chunk transition products ----------------
// grid: GG*NC = 2048 blocks, 64 threads (1 wave, lane = d).
__global__ __launch_bounds__(64) void k3_scanA(
    const bf* __restrict__ delta_ws, const bf* __restrict__ u_ws, const bf* __restrict__ Bws,
    const float* __restrict__ A_log, float* __restrict__ hloc, float* __restrict__ Aprod) {
  int s = blockIdx.x / NC, chunk = blockIdx.x % NC;
  int d = threadIdx.x;
  float A2[DSN];
#pragma unroll
  for (int n = 0; n < DSN; n++)
    A2[n] = -__expf(A_log[d * DSN + n]) * 1.44269504088896f;  // A * log2(e)
  bool ok = ladder_ok(A2);
  float h[DSN];
#pragma unroll
  for (int n = 0; n < DSN; n++) h[n] = 0.f;
  float ssum = 0.f;
  size_t base = (size_t)s * LL + (size_t)chunk * CL;
  const unsigned short* dp = (const unsigned short*)delta_ws + base * DI + d;
  const unsigned short* up = (const unsigned short*)u_ws + base * DI + d;
  const uint4* bp = (const uint4*)(Bws + base * DSN);
  if (ok) {
    float a0 = A2[0];
    for (int t = 0; t < CL; t++) {
      float delta = __uint_as_float((unsigned)dp[(size_t)t * DI] << 16);
      float uu    = __uint_as_float((unsigned)up[(size_t)t * DI] << 16);
      float Bv[16];
      unpack8(bp[t * 2], Bv); unpack8(bp[t * 2 + 1], Bv + 8);
      float du = delta * uu;
      ssum += delta;
      float E = EXP2F(delta * a0);
      float e = E;
#pragma unroll
      for (int n = 0; n < DSN; n++) {
        h[n] = fmaf(h[n], e, du * Bv[n]);
        e *= E;
      }
    }
  } else {
    for (int t = 0; t < CL; t++) {
      float delta = __uint_as_float((unsigned)dp[(size_t)t * DI] << 16);
      float uu    = __uint_as_float((unsigned)up[(size_t)t * DI] << 16);
      float Bv[16];
      unpack8(bp[t * 2], Bv); unpack8(bp[t * 2 + 1], Bv + 8);
      float du = delta * uu;
      ssum += delta;
#pragma unroll
      for (int n = 0; n < DSN; n++) {
        float e = EXP2F(delta * A2[n]);
        h[n] = fmaf(h[n], e, du * Bv[n]);
      }
    }
  }
  size_t ob = (size_t)blockIdx.x * (DSN * DI) + d;
#pragma unroll
  for (int n = 0; n < DSN; n++) {
    hloc[ob + n * DI] = h[n];
    Aprod[ob + n * DI] = EXP2F(A2[n] * ssum);
  }
}

// ---------------- K4: sequential cross-chunk combine -> per-chunk initial states ----------------
// grid: GG blocks, 64 threads.
__global__ __launch_bounds__(64) void k4_combine(
    const float* __restrict__ hloc, const float* __restrict__ Aprod, float* __restrict__ hin) {
  int s = blockIdx.x, d = threadIdx.x;
  float h[DSN];
#pragma unroll
  for (int n = 0; n < DSN; n++) h[n] = 0.f;
  for (int k = 0; k < NC; k++) {
    size_t base = (size_t)(s * NC + k) * (DSN * DI) + d;
#pragma unroll
    for (int n = 0; n < DSN; n++) {
      hin[base + n * DI] = h[n];
      h[n] = fmaf(h[n], Aprod[base + n * DI], hloc[base + n * DI]);
    }
  }
}

// ---------------- K5: scan pass C — replay with h_in, emit y2 = y + u*D (bf16, in-place over delta) ----------------
// grid: GG*NC = 2048 blocks, 64 threads.
__global__ __launch_bounds__(64) void k5_scanC(
    bf* dy, const bf* __restrict__ u_ws,
    const bf* __restrict__ Bws, const bf* __restrict__ Cws,
    const float* __restrict__ A_log, const float* __restrict__ Dw,
    const float* __restrict__ hin) {
  int s = blockIdx.x / NC, chunk = blockIdx.x % NC;
  int d = threadIdx.x;
  float A2[DSN];
#pragma unroll
  for (int n = 0; n < DSN; n++)
    A2[n] = -__expf(A_log[d * DSN + n]) * 1.44269504088896f;
  bool ok = ladder_ok(A2);
  float Dd = Dw[d];
  float h[DSN];
  size_t hb = (size_t)blockIdx.x * (DSN * DI) + d;
#pragma unroll
  for (int n = 0; n < DSN; n++) h[n] = hin[hb + n * DI];
  size_t base = (size_t)s * LL + (size_t)chunk * CL;
  unsigned short* dyp = (unsigned short*)dy + base * DI + d;
  const unsigned short* up = (const unsigned short*)u_ws + base * DI + d;
  const uint4* bp = (const uint4*)(Bws + base * DSN);
  const uint4* cp = (const uint4*)(Cws + base * DSN);
  if (ok) {
    float a0 = A2[0];
    for (int t = 0; t < CL; t++) {
      float delta = __uint_as_float((unsigned)dyp[(size_t)t * DI] << 16);
      float uu    = __uint_as_float((unsigned)up[(size_t)t * DI] << 16);
      float Bv[16], Cv[16];
      unpack8(bp[t * 2], Bv); unpack8(bp[t * 2 + 1], Bv + 8);
      unpack8(cp[t * 2], Cv); unpack8(cp[t * 2 + 1], Cv + 8);
      float du = delta * uu;
      float y = 0.f;
      float E = EXP2F(delta * a0);
      float e = E;
#pragma unroll
      for (int n = 0; n < DSN; n++) {
        h[n] = fmaf(h[n], e, du * Bv[n]);
        y = fmaf(h[n], Cv[n], y);
        e *= E;
      }
      bf r = f2bf(y + uu * Dd);
      dyp[(size_t)t * DI] = *(unsigned short*)&r;
    }
  } else {
    for (int t = 0; t < CL; t++) {
      float delta = __uint_as_float((unsigned)dyp[(size_t)t * DI] << 16);
      float uu    = __uint_as_float((unsigned)up[(size_t)t * DI] << 16);
      float Bv[16], Cv[16];
      unpack8(bp[t * 2], Bv); unpack8(bp[t * 2 + 1], Bv + 8);
      unpack8(cp[t * 2], Cv); unpack8(cp[t * 2 + 1], Cv + 8);
      float du = delta * uu;
      float y = 0.f;
#pragma unroll
      for (int n = 0; n < DSN; n++) {
        float e = EXP2F(delta * A2[n]);
        h[n] = fmaf(h[n], e, du * Bv[n]);
        y = fmaf(h[n], Cv[n], y);
      }
      bf r = f2bf(y + uu * Dd);
      dyp[(size_t)t * DI] = *(unsigned short*)&r;
    }
  }
}

// ---------------- K6: z-gate + out_proj + residual -> output (fp32). Reads xn(bf16), y2(bf16). ----------------
// grid: BB * (LL/TL) = 1024 blocks, 256 threads; thread = (g, column j).
__global__ __launch_bounds__(256) void k6_final(
    const bf* __restrict__ xn_ws, const float* __restrict__ in_proj_w,
    const float* __restrict__ out_proj_w, const bf* __restrict__ y2ws,
    float* __restrict__ out) {
  __shared__ unsigned short xnS[CC][66];   // row stride 33 dwords (odd) -> conflict-free
  __shared__ unsigned y2S[4][64 * 33];     // per-g: 64 rows x 32 dwords, stride 33
  int b = blockIdx.x >> 6;
  int tile = blockIdx.x & 63;
  int l0 = tile * TL;
  int tid = threadIdx.x;
  const unsigned* xsrc = (const unsigned*)xn_ws;
#pragma unroll
  for (int k = 0; k < 16; k++) {           // xn tile: 4096 dwords, coalesced
    int idx = tid + k * 256;
    int c = idx >> 5, dw = idx & 31;
    ((unsigned*)&xnS[c][0])[dw] = xsrc[(((size_t)(b * CC + c)) * LL + l0) / 2 + dw];
  }
#pragma unroll
  for (int k = 0; k < 32; k++) {           // y2 tile: 8192 dwords, coalesced per g-chunk
    int idx = tid + k * 256;
    int g = idx >> 11, rem = idx & 2047;
    const unsigned* ysrc = (const unsigned*)(y2ws + (((size_t)(g * BB + b)) * LL + l0) * DI);
    y2S[g][(rem >> 5) * 33 + (rem & 31)] = ysrc[rem];
  }
  __syncthreads();
  int j = tid & 63, g = tid >> 6;
  float xcol[32];
#pragma unroll
  for (int r = 0; r < 32; r++)
    xcol[r] = __uint_as_float((unsigned)xnS[g * 32 + r][j] << 16);
  float acc[DI];
  for (int d = 0; d < DI; d++) {           // z projection; weights wave-uniform -> s_load
    const float* w = in_proj_w + (DI + d) * DM;
    float a = 0.f;
#pragma unroll
    for (int r = 0; r < 32; r++) a = fmaf(xcol[r], w[r], a);
    acc[d] = a;
  }
  const unsigned* yrow = &y2S[g][j * 33];  // banks (j+k)%32, conflict-free
#pragma unroll
  for (int k = 0; k < 32; k++) {           // gate: y3 = y2 * silu(z)
    unsigned v = yrow[k];
    float z0 = acc[2 * k], z1 = acc[2 * k + 1];
    acc[2 * k]     = blo(v) * (z0 * sigmoidf_(z0));
    acc[2 * k + 1] = bhi(v) * (z1 * sigmoidf_(z1));
  }
  float* ob = out + ((size_t)(b * CC + g * DM)) * LL + l0 + j;
  for (int jj = 0; jj < DM; jj++) {        // out_proj + residual; weights uniform -> s_load
    const float* w = out_proj_w + jj * DI;
    float a = __uint_as_float((unsigned)xnS[g * 32 + jj][j] << 16);  // residual xn
#pragma unroll
    for (int d = 0; d < DI; d++) a = fmaf(acc[d], w[d], a);
    ob[(size_t)jj * LL] = a;               // lanes j-consecutive: coalesced 256B
  }
}

extern "C" void kernel_launch(void* const* d_in, const int* in_sizes, int n_in,
                              void* d_out, int out_size, void* d_ws, size_t ws_size,
                              hipStream_t stream) {
  const float* input     = (const float*)d_in[0];
  const float* ln_g      = (const float*)d_in[1];
  const float* ln_b      = (const float*)d_in[2];
  const float* in_proj_w = (const float*)d_in[3];
  const float* conv_w    = (const float*)d_in[4];
  const float* conv_b    = (const float*)d_in[5];
  const float* x_proj_w  = (const float*)d_in[6];
  const float* dt_proj_w = (const float*)d_in[7];
  const float* dt_proj_b = (const float*)d_in[8];
  const float* A_log     = (const float*)d_in[9];
  const float* Dw        = (const float*)d_in[10];
  const float* out_proj_w= (const float*)d_in[11];
  float* out = (float*)d_out;

  char* ws = (char*)d_ws;
  bf*    u_ws     = (bf*)(ws);                    // 32 MiB
  bf*    delta_ws = (bf*)(ws + 33554432);         // 32 MiB (y2 aliases after k5)
  bf*    Bws      = (bf*)(ws + 67108864);         // 8 MiB
  bf*    Cws      = (bf*)(ws + 75497472);         // 8 MiB
  bf*    xn_ws    = (bf*)(ws + 83886080);         // 16 MiB
  float* hloc     = (float*)(ws + 100663296);     // 8 MiB
  float* Aprod    = (float*)(ws + 109051904);     // 8 MiB
  float* hin      = (float*)(ws + 117440512);     // 8 MiB
  (void)in_sizes; (void)n_in; (void)out_size; (void)ws_size;

  hipLaunchKernelGGL(k1_ln_conv, dim3(1024), dim3(256), 0, stream,
                     input, ln_g, ln_b, in_proj_w, conv_w, conv_b, u_ws, xn_ws);
  hipLaunchKernelGGL(k2_xproj, dim3(1024), dim3(256), 0, stream,
                     u_ws, x_proj_w, dt_proj_w, dt_proj_b, delta_ws, Bws, Cws);
  hipLaunchKernelGGL(k3_scanA, dim3(GG * NC), dim3(64), 0, stream,
                     delta_ws, u_ws, Bws, A_log, hloc, Aprod);
  hipLaunchKernelGGL(k4_combine, dim3(GG), dim3(64), 0, stream,
                     hloc, Aprod, hin);
  hipLaunchKernelGGL(k5_scanC, dim3(GG * NC), dim3(64), 0, stream,
                     delta_ws, u_ws, Bws, Cws, A_log, Dw, hin);
  hipLaunchKernelGGL(k6_final, dim3(1024), dim3(256), 0, stream,
                     xn_ws, in_proj_w, out_proj_w, delta_ws, out);
}